// Round 3
// baseline (51.840 us; speedup 1.0000x reference)
//
#include <hip/hip_runtime.h>
#include <hip/hip_bf16.h>
#include <stdint.h>

typedef short short8 __attribute__((ext_vector_type(8)));
typedef float f32x4 __attribute__((ext_vector_type(4)));
typedef unsigned short ushort4_t __attribute__((ext_vector_type(4)));
typedef unsigned short ushort8_t __attribute__((ext_vector_type(8)));

#define S_LEN 2048
#define NQKV 1536
#define DMODEL 512

__device__ inline unsigned short f2bf(float f) {
  unsigned int u = __float_as_uint(f);
  unsigned int r = (u + 0x7FFFu + ((u >> 16) & 1u)) >> 16;
  return (unsigned short)r;
}

// async global->LDS, 16B per lane. LDS dest must be linear in lane order.
__device__ __forceinline__ void gll16(const unsigned short* g, unsigned short* l) {
  __builtin_amdgcn_global_load_lds(
      (const __attribute__((address_space(1))) unsigned int*)g,
      (__attribute__((address_space(3))) unsigned int*)l, 16, 0, 0);
}

// ---------------- fused prep: x->bf16, both weight transposes ----------------
__global__ __launch_bounds__(256) void k_prep(const float* __restrict__ x,
                                              unsigned short* __restrict__ xb,
                                              const float* __restrict__ w1,
                                              unsigned short* __restrict__ o1,
                                              const float* __restrict__ w2,
                                              unsigned short* __restrict__ o2) {
  __shared__ float T[32][33];
  int bid = blockIdx.x;
  int t = threadIdx.x;
  if (bid < 1024) {
    int i = (bid * 256 + t) * 8;
    float4 a = *(const float4*)(x + i);
    float4 b = *(const float4*)(x + i + 4);
    ushort8_t o;
    o[0] = f2bf(a.x); o[1] = f2bf(a.y); o[2] = f2bf(a.z); o[3] = f2bf(a.w);
    o[4] = f2bf(b.x); o[5] = f2bf(b.y); o[6] = f2bf(b.z); o[7] = f2bf(b.w);
    *(ushort8_t*)(xb + i) = o;
    return;
  }
  bid -= 1024;                       // 1024 transpose blocks: 64 x 16
  int bx = bid & 63, byy = bid >> 6;
  const float* w; unsigned short* o; int cols;
  if (bx < 48) { w = w1; o = o1; cols = 1536; }
  else         { w = w2; o = o2; cols = 512; bx -= 48; }
  int r0 = byy * 32, c0 = bx * 32;
  int tr = t / 32, tc = t % 32;
#pragma unroll
  for (int i = 0; i < 4; i++) {
    int r = tr + i * 8;
    T[r][tc] = w[(size_t)(r0 + r) * cols + c0 + tc];
  }
  __syncthreads();
#pragma unroll
  for (int i = 0; i < 4; i++) {
    int rr = tr + i * 8;
    o[(size_t)(c0 + rr) * 512 + r0 + tc] = f2bf(T[tc][rr]);
  }
}

// ---------------- GEMM: C[M][N] = A[M][K](bf16) * Bt[N][K](bf16)^T ----------------
// BMx128 tile, BK=32, 4 waves, global_load_lds staging, 2-phase double buffer.
// MODE 0: f32 out + bias.  MODE 1: bf16 qkv out, with V-third scattered to vT.
template <int BM, int MODE>
__global__ __launch_bounds__(256) void k_gemm(const unsigned short* __restrict__ A,
                                              const unsigned short* __restrict__ Bt,
                                              void* __restrict__ Cout,
                                              const float* __restrict__ bias,
                                              unsigned short* __restrict__ vt,
                                              int M, int N, int K) {
  constexpr int MR = BM / 32;
  constexpr int CA = BM / 64;
  __shared__ __align__(16) unsigned short As[2][BM * 32];
  __shared__ __align__(16) unsigned short Bs[2][128 * 32];
  const int t = threadIdx.x, lane = t & 63, wid = t >> 6;
  // bijective XCD swizzle (nwg % 8 == 0 for both launches)
  int id = blockIdx.y * gridDim.x + blockIdx.x;
  int cpx = (gridDim.x * gridDim.y) >> 3;
  int nid = (id & 7) * cpx + (id >> 3);
  const int m0 = (nid / gridDim.x) * BM, n0 = (nid % gridDim.x) * 128;
  const int wm = (wid >> 1) * (BM / 2), wn = (wid & 1) * 64;
  const int lr = lane & 15, kr = (lane >> 4) * 8, lg = lane >> 4;
  const unsigned short* Ab = A + (size_t)m0 * K;
  const unsigned short* Bb = Bt + (size_t)n0 * K;
  f32x4 acc[MR][4] = {};

  const int NT = K / 32;
  auto stage = [&](int buf, int kt) {
#pragma unroll
    for (int c = 0; c < CA; c++) {
      int f = t + 256 * c;
      gll16(Ab + (size_t)(f >> 2) * K + kt + (f & 3) * 8, &As[buf][f * 8]);
    }
#pragma unroll
    for (int c = 0; c < 2; c++) {
      int f = t + 256 * c;
      gll16(Bb + (size_t)(f >> 2) * K + kt + (f & 3) * 8, &Bs[buf][f * 8]);
    }
  };

  stage(0, 0);
  int buf = 0;
  for (int it = 0; it < NT; ++it) {
    __syncthreads();
    if (it + 1 < NT) stage(buf ^ 1, (it + 1) * 32);
    short8 af[MR], bfv[4];
#pragma unroll
    for (int i = 0; i < MR; i++)
      af[i] = *(const short8*)&As[buf][(wm + i * 16 + lr) * 32 + kr];
#pragma unroll
    for (int i = 0; i < 4; i++)
      bfv[i] = *(const short8*)&Bs[buf][(wn + i * 16 + lr) * 32 + kr];
#pragma unroll
    for (int mi = 0; mi < MR; mi++)
#pragma unroll
      for (int ni = 0; ni < 4; ni++)
        acc[mi][ni] = __builtin_amdgcn_mfma_f32_16x16x32_bf16(af[mi], bfv[ni], acc[mi][ni], 0, 0, 0);
    buf ^= 1;
  }

#pragma unroll
  for (int mi = 0; mi < MR; mi++) {
#pragma unroll
    for (int ni = 0; ni < 4; ni++) {
      int col = n0 + wn + ni * 16 + lr;
      if (MODE == 0) {
        float bv = bias[col];
#pragma unroll
        for (int j = 0; j < 4; j++) {
          int row = m0 + wm + mi * 16 + lg * 4 + j;
          ((float*)Cout)[(size_t)row * N + col] = acc[mi][ni][j] + bv;
        }
      } else {
        int hh = col / 192, rr = col % 192;
#pragma unroll
        for (int j = 0; j < 4; j++) {
          int row = m0 + wm + mi * 16 + lg * 4 + j;
          unsigned short bv = f2bf(acc[mi][ni][j]);
          if (rr < 128) {
            ((unsigned short*)Cout)[(size_t)row * N + col] = bv;
          } else {
            int bb = row >> 11, pos = row & 2047;
            vt[((size_t)((bb * 8 + hh) * 64 + (rr - 128))) * 2048 + pos] = bv;
          }
        }
      }
    }
  }
}

// ---------------- windowed attention (no LDS, no barriers) ----------------
// One wave per 16 queries. Scores computed transposed: S^T[pos][q] = mfma(K, Q).
// PV via O^T = mfma(V^T, P^T); V^T read from vT global; P^T rebuilt in-register.
__global__ __launch_bounds__(256) void k_attn(const unsigned short* __restrict__ qkv,
                                              const unsigned short* __restrict__ vT,
                                              unsigned short* __restrict__ attn) {
  const int t = threadIdx.x, lane = t & 63, w = t >> 6;
  const int blk = blockIdx.x;
  const int sbi = blk & 31, h = (blk >> 5) & 7, b = blk >> 8;
  const int sb = sbi * 64;
  const unsigned short* base = qkv + (size_t)b * S_LEN * NQKV;
  const int lr = lane & 15, lg = lane >> 4;
  const int s0 = sb + w * 16;

  // Q B-frags: lane holds Q[s0+lr][ks*32 + lg*8 .. +7]   (n=q=lr, k=dim)
  short8 qb[2];
#pragma unroll
  for (int ks = 0; ks < 2; ks++)
    qb[ks] = *(const short8*)(base + (size_t)(s0 + lr) * NQKV + h * 192 + ks * 32 + lg * 8);

  // S^T: 5 pos-tiles of 16. A-frag = K rows (m=pos=lr within tile, k=dim).
  f32x4 sc[5] = {};
#pragma unroll
  for (int ct = 0; ct < 5; ct++) {
    int p = s0 - 32 + ct * 16 + lr;
    bool inb = (p >= 0 && p < S_LEN);
#pragma unroll
    for (int ks = 0; ks < 2; ks++) {
      short8 ka = {};
      if (inb)
        ka = *(const short8*)(base + (size_t)p * NQKV + h * 192 + 64 + ks * 32 + lg * 8);
      sc[ct] = __builtin_amdgcn_mfma_f32_16x16x32_bf16(ka, qb[ks], sc[ct], 0, 0, 0);
    }
  }

  // Band mask + scale. C layout: col = q = lr, row = pos_local = ct*16 + lg*4 + j.
  // Window: pos_local - lr in [0, 64]. OOB seq positions keep score 0 (zero K).
  float mx = -1e30f;
#pragma unroll
  for (int ct = 0; ct < 5; ct++)
#pragma unroll
    for (int j = 0; j < 4; j++) {
      int c2 = ct * 16 + lg * 4 + j;
      sc[ct][j] = (c2 >= lr && c2 <= lr + 64) ? sc[ct][j] * 0.125f : -1e30f;
      mx = fmaxf(mx, sc[ct][j]);
    }
  mx = fmaxf(mx, __shfl_xor(mx, 16, 64));
  mx = fmaxf(mx, __shfl_xor(mx, 32, 64));

  float pn[5][4];
  float sum = 0.0f;
#pragma unroll
  for (int ct = 0; ct < 5; ct++)
#pragma unroll
    for (int j = 0; j < 4; j++) {
      pn[ct][j] = __expf(sc[ct][j] - mx);
      sum += pn[ct][j];
    }
  sum += __shfl_xor(sum, 16, 64);
  sum += __shfl_xor(sum, 32, 64);
  float inv = 1.0f / sum;

  // Pack P^T to bf16 pairs; zero OOB positions (reference multiplies them by V=0).
  unsigned int w01[5], w23[5];
#pragma unroll
  for (int ct = 0; ct < 5; ct++) {
    float v[4];
#pragma unroll
    for (int j = 0; j < 4; j++) {
      int p = s0 - 32 + ct * 16 + lg * 4 + j;
      float xv = pn[ct][j] * inv;
      v[j] = (p >= 0 && p < S_LEN) ? xv : 0.0f;
    }
    w01[ct] = (unsigned int)f2bf(v[0]) | ((unsigned int)f2bf(v[1]) << 16);
    w23[ct] = (unsigned int)f2bf(v[2]) | ((unsigned int)f2bf(v[3]) << 16);
  }

  // PV: O^T[d][q], contraction over 96 pos (3 k-slices of 32).
  const unsigned short* vbase = vT + (size_t)((b * 8 + h) * 64) * 2048;
  f32x4 oa[4] = {};
  const int h2 = lg & 1, tl = lg >> 1;
  const int sA = 32 * h2 + lr, sB = sA + 16;
#pragma unroll
  for (int ks = 0; ks < 3; ks++) {
    const int T0 = 2 * ks;
    const int T1 = (2 * ks + 1 < 5) ? (2 * ks + 1) : 4;
    unsigned int a0 = __shfl((int)w01[T0], sA, 64), a1 = __shfl((int)w23[T0], sA, 64);
    unsigned int a2 = __shfl((int)w01[T0], sB, 64), a3 = __shfl((int)w23[T0], sB, 64);
    unsigned int b0 = __shfl((int)w01[T1], sA, 64), b1 = __shfl((int)w23[T1], sA, 64);
    unsigned int b2 = __shfl((int)w01[T1], sB, 64), b3 = __shfl((int)w23[T1], sB, 64);
    union { unsigned int u[4]; short8 v; } pb;
    pb.u[0] = tl ? b0 : a0;
    pb.u[1] = tl ? b1 : a1;
    pb.u[2] = tl ? b2 : a2;
    pb.u[3] = tl ? b3 : a3;
    if (ks == 2 && tl) { pb.u[0] = 0; pb.u[1] = 0; pb.u[2] = 0; pb.u[3] = 0; }
    int poff = s0 - 32 + ks * 32 + lg * 8;
#pragma unroll
    for (int nt = 0; nt < 4; nt++) {
      short8 va = *(const short8*)(vbase + (size_t)(nt * 16 + lr) * 2048 + poff);
      oa[nt] = __builtin_amdgcn_mfma_f32_16x16x32_bf16(va, pb.v, oa[nt], 0, 0, 0);
    }
  }

  // Store: O^T row = d = nt*16 + lg*4 + j (4 consecutive d), col = q = lr.
#pragma unroll
  for (int nt = 0; nt < 4; nt++) {
    ushort4_t o;
#pragma unroll
    for (int j = 0; j < 4; j++) o[j] = f2bf(oa[nt][j]);
    *(ushort4_t*)(attn + ((size_t)b * S_LEN + s0 + lr) * DMODEL + h * 64 + nt * 16 + lg * 4) = o;
  }
}

// ---------------- launch ----------------
extern "C" void kernel_launch(void* const* d_in, const int* in_sizes, int n_in,
                              void* d_out, int out_size, void* d_ws, size_t ws_size,
                              hipStream_t stream) {
  const float* x    = (const float*)d_in[0];
  const float* Wqkv = (const float*)d_in[1];
  const float* Wout = (const float*)d_in[2];
  const float* bout = (const float*)d_in[3];
  char* ws = (char*)d_ws;
  unsigned short* xb    = (unsigned short*)(ws + 0);         // 4096x512 bf16   (4 MB)
  unsigned short* wqkvt = (unsigned short*)(ws + 4194304);   // 1536x512 bf16   (1.5 MB)
  unsigned short* woutt = (unsigned short*)(ws + 5767168);   // 512x512 bf16    (0.5 MB)
  unsigned short* qkv   = (unsigned short*)(ws + 6291456);   // 4096x1536 bf16  (12 MB)
  unsigned short* attn  = (unsigned short*)(ws + 18874368);  // 4096x512 bf16   (4 MB)
  unsigned short* vT    = (unsigned short*)(ws + 23068672);  // [2][8][64][2048] (4 MB)

  hipLaunchKernelGGL(k_prep, dim3(2048), dim3(256), 0, stream,
                     x, xb, Wqkv, wqkvt, Wout, woutt);
  hipLaunchKernelGGL((k_gemm<128, 1>), dim3(12, 32), dim3(256), 0, stream,
                     xb, wqkvt, (void*)qkv, (const float*)nullptr, vT, 4096, 1536, 512);
  hipLaunchKernelGGL(k_attn, dim3(512), dim3(256), 0, stream, qkv, vT, attn);
  hipLaunchKernelGGL((k_gemm<64, 0>), dim3(4, 64), dim3(256), 0, stream,
                     attn, woutt, d_out, bout, (unsigned short*)nullptr, 4096, 512, 512);
}